// Round 4
// baseline (452.718 us; speedup 1.0000x reference)
//
#include <hip/hip_runtime.h>
#include <math.h>

// ---------------- problem constants ----------------
#define N_   32
#define NUP_ 16
#define M_   4
#define D_   128
#define K_   64
#define F_   32
#define H_   45
#define L_   3
#define LOG2_ 0.69314718055994530942f

typedef __attribute__((ext_vector_type(8))) short short8;
typedef __attribute__((ext_vector_type(4))) float float4v;

__device__ __forceinline__ float ssp(float v) {
    return __logf(1.0f + __expf(v)) - LOG2_;   // ssp(0)==0 exactly
}

__device__ __forceinline__ unsigned short f2bf(float x) {   // RTNE, prep only
    unsigned int u = __float_as_uint(x);
    return (unsigned short)((u + 0x7FFFu + ((u >> 16) & 1u)) >> 16);
}

// pack two floats -> bf16x2 (round-half-up)
__device__ __forceinline__ unsigned int pkbf(float x, float y) {
    return __builtin_amdgcn_perm(__float_as_uint(y) + 0x8000u,
                                 __float_as_uint(x) + 0x8000u, 0x07060302u);
}

// ---------------- prep: pack weights into MFMA B-fragment order ----------------
// w1B[lc][nt:3][512]        k=(lane>>4)*8+jj (f), n=nt*16+(lane&15) (hidden)
// w2B[lc][ks:2][nt:4][512]  k=p (hidden position 4*l16+nt), p==3 -> bias row
// gB [l][ks:6][nt:8][512]   k=c*64+kk, n=d
// hB [li:2][ks:4][nt:4][512] k=d (identity), n=kout  (hW layers 1,2)
// gbs[l][128] = sum_c gb[l][c][:]
__global__ __launch_bounds__(256) void prep_kernel(
    const float* __restrict__ wW1, const float* __restrict__ wW2,
    const float* __restrict__ wb2, const float* __restrict__ gW,
    const float* __restrict__ hW,  const float* __restrict__ gb,
    short* __restrict__ w1B, short* __restrict__ w2B,
    short* __restrict__ gB,  short* __restrict__ hB, float* __restrict__ gbs)
{
    int blk = blockIdx.x;
    int t = threadIdx.x;
    if (blk < 27) {                       // w1B
        int lc = blk / 3, nt = blk % 3;
        short* dst = w1B + (size_t)blk * 512;
        for (int idx = t; idx < 512; idx += 256) {
            int lane = idx >> 3, jj = idx & 7;
            int k = ((lane >> 4) << 3) + jj;
            int n = nt * 16 + (lane & 15);
            float v = (n < H_) ? wW1[((size_t)lc * H_ + n) * F_ + k] : 0.0f;
            dst[idx] = (short)f2bf(v);
        }
    } else if (blk < 99) {                // w2B
        int b3 = blk - 27;
        int lc = b3 >> 3, rem = b3 & 7, ks = rem >> 2, nt = rem & 3;
        short* dst = w2B + (size_t)b3 * 512;
        for (int idx = t; idx < 512; idx += 256) {
            int lane = idx >> 3, jj = idx & 7;
            int p = ks * 32 + ((lane >> 4) << 3) + jj;
            int n = nt * 16 + (lane & 15);
            float v;
            if (p == 3) v = wb2[(size_t)lc * K_ + n];
            else if ((p & 3) < 3) {
                int u = (p & 3) * 16 + (p >> 2);
                v = (u < H_) ? wW2[((size_t)lc * K_ + n) * H_ + u] : 0.0f;
            } else v = 0.0f;
            dst[idx] = (short)f2bf(v);
        }
    } else if (blk < 243) {               // gB
        int g = blk - 99;
        int l = g / 48, rem = g % 48;
        short* dst = gB + (size_t)g * 512;
        for (int idx = t; idx < 512; idx += 256) {
            int lane = idx >> 3, jj = idx & 7;
            int k = (rem >> 3) * 32 + ((lane >> 4) << 3) + jj;
            int c = k >> 6, kk = k & 63;
            int n = ((rem & 7) * 16) + (lane & 15);
            dst[idx] = (short)f2bf(gW[(((size_t)l * 3 + c) * D_ + n) * K_ + kk]);
        }
    } else if (blk < 275) {               // hB (identity d-order)
        int hh = blk - 243;
        int li = hh >> 4, rem = hh & 15;
        short* dst = hB + (size_t)hh * 512;
        for (int idx = t; idx < 512; idx += 256) {
            int lane = idx >> 3, jj = idx & 7;
            int d = (rem >> 2) * 32 + ((lane >> 4) << 3) + jj;   // 0..127
            int n = ((rem & 3) * 16) + (lane & 15);
            dst[idx] = (short)f2bf(hW[(((size_t)(li + 1)) * K_ + n) * D_ + d]);
        }
    } else {                              // gbs
        for (int idx = t; idx < 384; idx += 256) {
            int l = idx >> 7, d = idx & 127;
            gbs[idx] = gb[((size_t)l * 3 + 0) * D_ + d]
                     + gb[((size_t)l * 3 + 1) * D_ + d]
                     + gb[((size_t)l * 3 + 2) * D_ + d];
        }
    }
}

// ---------------- h0 ----------------
__global__ __launch_bounds__(64) void h0_kernel(
    const float* __restrict__ X, const float* __restrict__ hW,
    const float* __restrict__ hb, float* __restrict__ h0)
{
    int k = threadIdx.x;
    float a = hb[k];
    const float* w = hW + (size_t)k * D_;
    #pragma unroll 8
    for (int dd = 0; dd < D_; ++dd) a += w[dd] * X[dd];
    h0[k] = a;
}

// ---------------- MFMA edge kernel: 8 waves/WG, one (b,i) per wave ----------------
#define HDS 72
__global__ __launch_bounds__(512, 5) void edge_kernel(
    const float* __restrict__ ee, const float* __restrict__ en,
    const float* __restrict__ Y,
    const short* __restrict__ w1B, const float* __restrict__ wb1,
    const short* __restrict__ w2B,
    const float* __restrict__ h, const float* __restrict__ h0,
    unsigned short* __restrict__ zb, int l, int hmode)
{
    __shared__ float wrowT[36 * 64];              // 9216 B, [j][l16][m]
    __shared__ short hd_s[8][16 * HDS];           // 18432 B
    __shared__ float part_s[8][256];              // 8192 B

    const int tid  = threadIdx.x;
    const int wv   = tid >> 6;
    const int lane = tid & 63;
    const int quad = lane >> 4;
    const int l16  = lane & 15;
    const int b    = blockIdx.x >> 2;
    const int i    = ((blockIdx.x & 3) << 3) + wv;
    const int bi   = (b << 5) + i;

    // ---- stage wrowT[j][l16][m] = hsrc[j][m*16+l16] ----
    {
        int row = tid >> 4;                       // 0..31
        int c0 = (tid & 15) * 4;
        int m = c0 >> 4, lb = c0 & 15;
        const float* src = hmode ? (h + ((size_t)(b * N_ + row)) * K_ + c0) : (h0 + c0);
        float4 v = *(const float4*)src;
        wrowT[row * 64 + (lb + 0) * 4 + m] = v.x;
        wrowT[row * 64 + (lb + 1) * 4 + m] = v.y;
        wrowT[row * 64 + (lb + 2) * 4 + m] = v.z;
        wrowT[row * 64 + (lb + 3) * 4 + m] = v.w;
        if (tid < 64) {
            int r2 = 32 + (tid >> 4);
            float4 y = *(const float4*)(Y + ((size_t)(tid >> 4)) * K_ + c0);
            wrowT[r2 * 64 + (lb + 0) * 4 + m] = y.x;
            wrowT[r2 * 64 + (lb + 1) * 4 + m] = y.y;
            wrowT[r2 * 64 + (lb + 2) * 4 + m] = y.z;
            wrowT[r2 * 64 + (lb + 3) * 4 + m] = y.w;
        }
    }
    __syncthreads();

    const int cA = (i < NUP_) ? 0 : 1;
    const int cs0 = cA, cs1 = 1 - cA, cs2 = 2;
    short* hd = hd_s[wv];
    float* part = part_s[wv];
    const unsigned int cpad = (l16 == 0) ? 0x3F808000u : 0u;  // bf16 1.0 in bias slot

    // ---- prefetch all A-fragments (rows t*16+l16, cols quad*8..+7) ----
    const float* ep = ee + (((size_t)bi * N_) + l16) * F_ + quad * 8;
    float4 e0a = *(const float4*)(ep);
    float4 e0b = *(const float4*)(ep + 4);
    float4 e1a = *(const float4*)(ep + 16 * F_);
    float4 e1b = *(const float4*)(ep + 16 * F_ + 4);
    float4 e2a = {0.f,0.f,0.f,0.f}, e2b = {0.f,0.f,0.f,0.f};
    if (l16 < M_) {
        const float* np = en + (((size_t)bi * M_) + l16) * F_ + quad * 8;
        e2a = *(const float4*)(np);
        e2b = *(const float4*)(np + 4);
    }
    // ---- prefetch stage-1 biases ----
    float b1r[9];
    {
        const int cls[3] = {l * 3 + cs0, l * 3 + cs1, l * 3 + cs2};
        #pragma unroll
        for (int t = 0; t < 3; ++t)
            #pragma unroll
            for (int nt = 0; nt < 3; ++nt) {
                int col = nt * 16 + l16;
                b1r[t * 3 + nt] = (col < H_) ? wb1[(size_t)cls[t] * H_ + col] : 0.0f;
            }
    }
    union { short8 s; unsigned int u[4]; } A[3];
    A[0].u[0] = pkbf(e0a.x, e0a.y); A[0].u[1] = pkbf(e0a.z, e0a.w);
    A[0].u[2] = pkbf(e0b.x, e0b.y); A[0].u[3] = pkbf(e0b.z, e0b.w);
    A[1].u[0] = pkbf(e1a.x, e1a.y); A[1].u[1] = pkbf(e1a.z, e1a.w);
    A[1].u[2] = pkbf(e1b.x, e1b.y); A[1].u[3] = pkbf(e1b.z, e1b.w);
    A[2].u[0] = pkbf(e2a.x, e2a.y); A[2].u[1] = pkbf(e2a.z, e2a.w);
    A[2].u[2] = pkbf(e2b.x, e2b.y); A[2].u[3] = pkbf(e2b.z, e2b.w);

    #pragma unroll
    for (int t = 0; t < 3; ++t) {
        const int c  = (t == 0) ? cs0 : ((t == 1) ? cs1 : cs2);
        const int lc = l * 3 + c;

        // ---- stage 1 ----
        float4v acc1[3];
        #pragma unroll
        for (int nt = 0; nt < 3; ++nt) {
            float b1c = b1r[t * 3 + nt];
            acc1[nt] = (float4v){b1c, b1c, b1c, b1c};
            short8 bf = *(const short8*)(w1B + (((size_t)lc * 3 + nt) << 9) + (lane << 3));
            acc1[nt] = __builtin_amdgcn_mfma_f32_16x16x32_bf16(A[t].s, bf, acc1[nt], 0, 0, 0);
        }

        // ---- ssp + packed b64 hidden write (pos 4*l16+nt, bias slot 1.0) ----
        #pragma unroll
        for (int r = 0; r < 4; ++r) {
            float s0 = ssp(acc1[0][r]);
            float s1 = ssp(acc1[1][r]);
            float s2 = ssp(acc1[2][r]);
            unsigned int lo = pkbf(s0, s1);
            unsigned int hi = __builtin_amdgcn_perm(cpad, __float_as_uint(s2) + 0x8000u, 0x07060302u);
            uint2 pr; pr.x = lo; pr.y = hi;
            *(uint2*)(hd + (quad * 4 + r) * HDS + 4 * l16) = pr;
        }

        // ---- stage 2 ----
        float4v acc2[4];
        #pragma unroll
        for (int nt = 0; nt < 4; ++nt) acc2[nt] = (float4v){0.f, 0.f, 0.f, 0.f};
        #pragma unroll
        for (int ks = 0; ks < 2; ++ks) {
            short8 a2 = *(const short8*)(hd + l16 * HDS + ks * 32 + quad * 8);
            #pragma unroll
            for (int nt = 0; nt < 4; ++nt) {
                short8 bf = *(const short8*)(w2B + ((((size_t)lc * 2 + ks) * 4 + nt) << 9) + (lane << 3));
                acc2[nt] = __builtin_amdgcn_mfma_f32_16x16x32_bf16(a2, bf, acc2[nt], 0, 0, 0);
            }
        }

        // ---- epilogue: msg * h, partial over this quad's rows ----
        float p0 = 0.f, p1 = 0.f, p2 = 0.f, p3 = 0.f;
        #pragma unroll
        for (int r = 0; r < 4; ++r) {
            int jrow = t * 16 + quad * 4 + r;
            int jcl = (jrow < 36) ? jrow : 35;
            float4 wv4 = *(const float4*)(wrowT + jcl * 64 + l16 * 4);
            bool live = (t == 2) ? (jrow < 36) : (jrow != i);
            if (!live) { wv4.x = 0.f; wv4.y = 0.f; wv4.z = 0.f; wv4.w = 0.f; }
            p0 += acc2[0][r] * wv4.x;
            p1 += acc2[1][r] * wv4.y;
            p2 += acc2[2][r] * wv4.z;
            p3 += acc2[3][r] * wv4.w;
        }
        // quad-partial reduce through LDS (wave-local)
        float4 pv; pv.x = p0; pv.y = p1; pv.z = p2; pv.w = p3;
        *(float4*)(&part[(quad * 16 + l16) * 4]) = pv;
        __builtin_amdgcn_s_waitcnt(0);     // lgkmcnt(0): wave-local LDS RAW
        float zsum = part[l16 * 4 + quad] + part[64 + l16 * 4 + quad]
                   + part[128 + l16 * 4 + quad] + part[192 + l16 * 4 + quad];
        zb[(size_t)bi * 192 + c * 64 + lane] =
            (unsigned short)((__float_as_uint(zsum) + 0x8000u) >> 16);
    }
}

// ---------------- MFMA fuse: 3-wave K-split; vectorized residual ----------------
#define XPS 132   // floats per xpart row (pad for banks)
#define HXS 136   // shorts per hx row
__global__ __launch_bounds__(192, 4) void fuse_kernel(
    const unsigned short* __restrict__ zb, const short* __restrict__ gB,
    const float* __restrict__ gbs, const float* __restrict__ X,
    const short* __restrict__ hB, const float* __restrict__ hb,
    float* __restrict__ xout, float* __restrict__ hout,
    int l, int first, int compute_h)
{
    __shared__ float xpart[3][16 * XPS];   // 25344 B
    __shared__ short hx[16 * HXS];         // 4352 B

    const int tid  = threadIdx.x;
    const int wv   = tid >> 6;             // 0..2 = channel c
    const int lane = tid & 63;
    const int quad = lane >> 4;
    const int l16  = lane & 15;
    const int bi0  = blockIdx.x * 16;

    // ---- Z @ Gc^T : this wave's channel, 2 K-steps x 8 column tiles ----
    float4v ax[8];
    #pragma unroll
    for (int nt = 0; nt < 8; ++nt) ax[nt] = (float4v){0.f, 0.f, 0.f, 0.f};
    const short* zrow = (const short*)zb + ((size_t)(bi0 + l16)) * 192;
    const short* gl = gB + (size_t)l * 48 * 512;
    #pragma unroll
    for (int ks2 = 0; ks2 < 2; ++ks2) {
        int ks = wv * 2 + ks2;
        short8 az = *(const short8*)(zrow + ks * 32 + quad * 8);
        #pragma unroll
        for (int nt = 0; nt < 8; ++nt) {
            short8 bf = *(const short8*)(gl + (((size_t)ks * 8 + nt) << 9) + (lane << 3));
            ax[nt] = __builtin_amdgcn_mfma_f32_16x16x32_bf16(az, bf, ax[nt], 0, 0, 0);
        }
    }
    // write partials chunked: xpart[wv][row][l16*8 + nt]
    float* xp = xpart[wv];
    #pragma unroll
    for (int r = 0; r < 4; ++r) {
        int row = quad * 4 + r;
        float4 lo; lo.x = ax[0][r]; lo.y = ax[1][r]; lo.z = ax[2][r]; lo.w = ax[3][r];
        float4 hi; hi.x = ax[4][r]; hi.y = ax[5][r]; hi.z = ax[6][r]; hi.w = ax[7][r];
        *(float4*)(&xp[row * XPS + l16 * 8])     = lo;
        *(float4*)(&xp[row * XPS + l16 * 8 + 4]) = hi;
    }
    __syncthreads();

    // ---- reduce + residual + store x (vectorized), pack hx ----
    if (tid < 128) {
        int row = tid >> 3, nt = tid & 7;
        int dbase = nt * 16;
        size_t gi = ((size_t)(bi0 + row)) * D_ + dbase;
        float acc[16];
        #pragma unroll
        for (int j = 0; j < 16; ++j) {
            int o = row * XPS + j * 8 + nt;
            acc[j] = xpart[0][o] + xpart[1][o] + xpart[2][o];
        }
        float res[16];
        #pragma unroll
        for (int q = 0; q < 4; ++q) {
            float4 rv = first ? *(const float4*)(X + dbase + q * 4)
                              : *(const float4*)(xout + gi + q * 4);
            float4 gv = *(const float4*)(gbs + (size_t)l * D_ + dbase + q * 4);
            res[q*4+0] = rv.x + gv.x; res[q*4+1] = rv.y + gv.y;
            res[q*4+2] = rv.z + gv.z; res[q*4+3] = rv.w + gv.w;
        }
        float xo[16];
        #pragma unroll
        for (int j = 0; j < 16; ++j) xo[j] = acc[j] + res[j];
        #pragma unroll
        for (int q = 0; q < 4; ++q) {
            float4 sv; sv.x = xo[q*4+0]; sv.y = xo[q*4+1]; sv.z = xo[q*4+2]; sv.w = xo[q*4+3];
            *(float4*)(xout + gi + q * 4) = sv;
        }
        if (compute_h) {
            union { short8 s; unsigned int u[4]; } P0, P1;
            P0.u[0] = pkbf(xo[0], xo[1]);  P0.u[1] = pkbf(xo[2], xo[3]);
            P0.u[2] = pkbf(xo[4], xo[5]);  P0.u[3] = pkbf(xo[6], xo[7]);
            P1.u[0] = pkbf(xo[8], xo[9]);  P1.u[1] = pkbf(xo[10], xo[11]);
            P1.u[2] = pkbf(xo[12], xo[13]); P1.u[3] = pkbf(xo[14], xo[15]);
            *(short8*)(hx + row * HXS + dbase)     = P0.s;
            *(short8*)(hx + row * HXS + dbase + 8) = P1.s;
        }
    }
    if (!compute_h) return;
    __syncthreads();

    // ---- h_next = x @ hW^T (redundant per wave; stores split) ----
    float4v ah[4];
    #pragma unroll
    for (int nt = 0; nt < 4; ++nt) ah[nt] = (float4v){0.f, 0.f, 0.f, 0.f};
    const short* hl = hB + (size_t)l * 16 * 512;
    #pragma unroll
    for (int ks = 0; ks < 4; ++ks) {
        short8 a = *(const short8*)(hx + l16 * HXS + ks * 32 + quad * 8);
        #pragma unroll
        for (int nt = 0; nt < 4; ++nt) {
            short8 bf = *(const short8*)(hl + (((size_t)ks * 4 + nt) << 9) + (lane << 3));
            ah[nt] = __builtin_amdgcn_mfma_f32_16x16x32_bf16(a, bf, ah[nt], 0, 0, 0);
        }
    }
    int nlo = (wv == 0) ? 0 : ((wv == 1) ? 2 : 3);
    int nhi = (wv == 0) ? 2 : (nlo + 1);
    for (int nt = nlo; nt < nhi; ++nt) {
        float hbv = hb[((size_t)(l + 1)) * K_ + nt * 16 + l16];
        #pragma unroll
        for (int r = 0; r < 4; ++r)
            hout[((size_t)(bi0 + quad * 4 + r)) * K_ + nt * 16 + l16] = ah[nt][r] + hbv;
    }
}

// ---------------- launch ----------------
extern "C" void kernel_launch(void* const* d_in, const int* in_sizes, int n_in,
                              void* d_out, int out_size, void* d_ws, size_t ws_size,
                              hipStream_t stream)
{
    const float* ee  = (const float*)d_in[0];
    const float* en  = (const float*)d_in[1];
    const float* X   = (const float*)d_in[2];
    const float* Y   = (const float*)d_in[3];
    const float* wW1 = (const float*)d_in[4];
    const float* wb1 = (const float*)d_in[5];
    const float* wW2 = (const float*)d_in[6];
    const float* wb2 = (const float*)d_in[7];
    const float* hW  = (const float*)d_in[8];
    const float* hb  = (const float*)d_in[9];
    const float* gW  = (const float*)d_in[10];
    const float* gb  = (const float*)d_in[11];
    float* xout = (float*)d_out;

    // workspace carve (all 16B-aligned)
    char* ws = (char*)d_ws;
    float*          h   = (float*)(ws);                         // 8,388,608 B
    unsigned short* zb  = (unsigned short*)(ws + 8388608);      // 12,582,912 B
    float*          h0  = (float*)(ws + 8388608 + 12582912);    // 256 B
    short*          w1B = (short*)(ws + 20971520 + 256);        // 27,648 B
    short*          w2B = w1B + (size_t)27 * 512;               // 73,728 B
    short*          gB  = w2B + (size_t)72 * 512;               // 147,456 B
    short*          hB  = gB  + (size_t)144 * 512;              // 32,768 B
    float*          gbs = (float*)(hB + (size_t)32 * 512);      // 1,536 B

    prep_kernel<<<276, 256, 0, stream>>>(wW1, wW2, wb2, gW, hW, gb,
                                         w1B, w2B, gB, hB, gbs);
    h0_kernel<<<1, 64, 0, stream>>>(X, hW, hb, h0);

    // layer 0
    edge_kernel<<<4096, 512, 0, stream>>>(ee, en, Y, w1B, wb1, w2B, h, h0, zb, 0, 0);
    fuse_kernel<<<2048, 192, 0, stream>>>(zb, gB, gbs, X, hB, hb, xout, h, 0, 1, 1);
    // layer 1
    edge_kernel<<<4096, 512, 0, stream>>>(ee, en, Y, w1B, wb1, w2B, h, h0, zb, 1, 1);
    fuse_kernel<<<2048, 192, 0, stream>>>(zb, gB, gbs, X, hB, hb, xout, h, 1, 0, 1);
    // layer 2
    edge_kernel<<<4096, 512, 0, stream>>>(ee, en, Y, w1B, wb1, w2B, h, h0, zb, 2, 1);
    fuse_kernel<<<2048, 192, 0, stream>>>(zb, gB, gbs, X, hB, hb, xout, h, 2, 0, 0);
}